// Round 1
// baseline (268.237 us; speedup 1.0000x reference)
//
#include <hip/hip_runtime.h>
#include <hip/hip_bf16.h>

#define N_ANCH 49104
#define NB 16
#define NGT 100
#define NC 80

__device__ __forceinline__ float frcp(float x){ return __builtin_amdgcn_rcpf(x); }

// focal term for one logit; is_t = this class is the one-hot target class
__device__ __forceinline__ float focal_term(float x, bool is_t){
  float e = expf(-fabsf(x));         // exp(-|x|) in (0,1]
  float l = log1pf(e);               // softplus(-|x|)
  float r = frcp(1.0f + e);          // 1/(1+e)
  float q = 1.0f - r;                // e/(1+e)
  bool xp = x >= 0.f;
  float p   = xp ? r : q;            // sigmoid(x)
  float omp = xp ? q : r;            // 1 - sigmoid(x)
  // t=1: 0.25*(1-p)^2*softplus(-x) ; t=0: 0.75*p^2*softplus(x)
  return is_t ? 0.25f * omp * omp * (fmaxf(-x, 0.f) + l)
              : 0.75f * p   * p   * (fmaxf( x, 0.f) + l);
}

__global__ __launch_bounds__(256) void anchor_loss_kernel(
    const float* __restrict__ cls,
    const float* __restrict__ bbox,
    const float* __restrict__ gtb,
    const int*   __restrict__ gtl,
    const unsigned char* __restrict__ gmask,
    double* __restrict__ S,     // [32]: S_cls[16], S_bbox[16]
    int* __restrict__ cnt)      // [16]: pos count per image
{
  const int tid = threadIdx.x;
  const int b   = blockIdx.y;
  const int a   = blockIdx.x * 256 + tid;

  __shared__ float4 s_gt[NGT];
  __shared__ float  s_area[NGT];
  __shared__ int    s_label[NGT];
  __shared__ int    s_valid[NGT];
  __shared__ int    s_notfloat, s_offbyte;
  __shared__ float  s_rc[4], s_rb[4];
  __shared__ int    s_rp[4];

  if (tid == 0){ s_notfloat = 0; s_offbyte = 0; }
  __syncthreads();

  // ---- detect mask_labels storage layout (bool8 vs int32 vs float32) ----
  // Safe to read only min size = 1600 bytes = 400 dwords.
  {
    const unsigned int* mw = (const unsigned int*)gmask;
    int nf = 0, ob = 0;
    for (int i = tid; i < (NB * NGT) / 4; i += 256){
      unsigned int w = mw[i];
      if (w != 0u && w != 0x3F800000u) nf = 1;   // not a {0,1.0f} float pattern
      if (w & 0xFFFFFF00u)             ob = 1;   // nonzero byte at off%4 != 0
    }
    if (nf) s_notfloat = 1;
    if (ob) s_offbyte  = 1;
  }
  __syncthreads();
  const bool byteLayout = (s_notfloat && s_offbyte);  // else: dword elements

  // ---- stage this image's GT boxes / labels / validity into LDS ----
  for (int j = tid; j < NGT; j += 256){
    float4 g = ((const float4*)gtb)[b * NGT + j];
    s_gt[j]   = g;
    s_area[j] = (g.z - g.x) * (g.w - g.y);
    s_label[j] = gtl[b * NGT + j];
    int v;
    if (byteLayout) v = (gmask[b * NGT + j] != 0);
    else            v = (((const unsigned int*)gmask)[b * NGT + j] != 0u);
    s_valid[j] = v;
  }
  __syncthreads();

  float accC = 0.f, accB = 0.f;
  int posi = 0;

  if (a < N_ANCH){
    // ---- regenerate anchor a (RetinaNet grid) ----
    int f, lg, st, rel;
    if      (a < 36864){ f = 64; lg = 6; st = 8;   rel = a; }
    else if (a < 46080){ f = 32; lg = 5; st = 16;  rel = a - 36864; }
    else if (a < 48384){ f = 16; lg = 4; st = 32;  rel = a - 46080; }
    else if (a < 48960){ f = 8;  lg = 3; st = 64;  rel = a - 48384; }
    else               { f = 4;  lg = 2; st = 128; rel = a - 48960; }
    int cell = rel / 9;
    int k    = rel - cell * 9;
    int yy   = cell >> lg;
    int xx   = cell & (f - 1);
    int rr = (k >= 6) ? 2 : ((k >= 3) ? 1 : 0);   // ratio index
    int sc = k - rr * 3;                          // scale index
    // f64 to match numpy's anchor gen, then cast to f32
    double sq  = (rr == 0) ? 0.7071067811865476 : ((rr == 1) ? 1.0 : 1.4142135623730951);
    double scl = (sc == 0) ? 4.0 : ((sc == 1) ? 5.039684199579493 : 6.349604207872798);
    double ss  = (double)st * scl;
    double wd  = ss / sq, hd = ss * sq;
    double cxd = ((double)xx + 0.5) * (double)st;
    double cyd = ((double)yy + 0.5) * (double)st;
    float x1 = (float)(cxd - wd * 0.5);
    float y1 = (float)(cyd - hd * 0.5);
    float x2 = (float)(cxd + wd * 0.5);
    float y2 = (float)(cyd + hd * 0.5);
    float areaA = (x2 - x1) * (y2 - y1);

    // ---- IoU vs 100 GTs, track first argmax ----
    float best_iou = -2.f; int best = 0;
    #pragma unroll 4
    for (int j = 0; j < NGT; ++j){
      float4 g = s_gt[j];
      float lx = fmaxf(x1, g.x), ly = fmaxf(y1, g.y);
      float rx = fminf(x2, g.z), ry = fminf(y2, g.w);
      float iw = fmaxf(rx - lx, 0.f), ih = fmaxf(ry - ly, 0.f);
      float inter = iw * ih;
      float un = fmaxf(areaA + s_area[j] - inter, 1e-6f);
      float iou = inter * frcp(un);
      iou = s_valid[j] ? iou : -1.0f;
      if (iou > best_iou){ best_iou = iou; best = j; }
    }

    bool pos = best_iou >= 0.5f;
    bool ign = (!pos) && (best_iou >= 0.4f);   // idx == -2: excluded from cls
    int label = -1;

    if (pos){
      posi = 1;
      label = s_label[best];
      float4 g = s_gt[best];
      // encode(gt, anchor), DeltaXYWH with unit stds
      float aw = x2 - x1, ah = y2 - y1;
      float axc = (x1 + x2) * 0.5f, ayc = (y1 + y2) * 0.5f;
      float gw = fmaxf(g.z - g.x, 1e-6f), gh = fmaxf(g.w - g.y, 1e-6f);
      float gxc = (g.x + g.z) * 0.5f, gyc = (g.y + g.w) * 0.5f;
      float t0 = (gxc - axc) / aw, t1 = (gyc - ayc) / ah;
      float t2 = logf(gw / aw),    t3 = logf(gh / ah);
      float4 bp = ((const float4*)bbox)[(size_t)b * N_ANCH + a];
      const float BETA = 1.0f / 9.0f;
      float d0 = fabsf(bp.x - t0), d1 = fabsf(bp.y - t1);
      float d2 = fabsf(bp.z - t2), d3 = fabsf(bp.w - t3);
      accB += (d0 < BETA) ? 0.5f * d0 * d0 / BETA : d0 - 0.5f * BETA;
      accB += (d1 < BETA) ? 0.5f * d1 * d1 / BETA : d1 - 0.5f * BETA;
      accB += (d2 < BETA) ? 0.5f * d2 * d2 / BETA : d2 - 0.5f * BETA;
      accB += (d3 < BETA) ? 0.5f * d3 * d3 / BETA : d3 - 0.5f * BETA;
    }

    if (!ign){
      const float4* cp = (const float4*)(cls + (size_t)(b * N_ANCH + a) * NC);
      #pragma unroll 5
      for (int v = 0; v < NC / 4; ++v){
        float4 c4 = cp[v];
        int cb = v * 4;
        accC += focal_term(c4.x, cb + 0 == label);
        accC += focal_term(c4.y, cb + 1 == label);
        accC += focal_term(c4.z, cb + 2 == label);
        accC += focal_term(c4.w, cb + 3 == label);
      }
    }
  }

  // ---- block reduction: wave shuffle then cross-wave via LDS ----
  #pragma unroll
  for (int o = 32; o > 0; o >>= 1){
    accC += __shfl_down(accC, o);
    accB += __shfl_down(accB, o);
    posi += __shfl_down(posi, o);
  }
  int wave = tid >> 6, lane = tid & 63;
  if (lane == 0){ s_rc[wave] = accC; s_rb[wave] = accB; s_rp[wave] = posi; }
  __syncthreads();
  if (tid == 0){
    float c  = s_rc[0] + s_rc[1] + s_rc[2] + s_rc[3];
    float bb = s_rb[0] + s_rb[1] + s_rb[2] + s_rb[3];
    int   p  = s_rp[0] + s_rp[1] + s_rp[2] + s_rp[3];
    atomicAdd(&S[b],      (double)c);
    atomicAdd(&S[NB + b], (double)bb);
    atomicAdd(&cnt[b], p);
  }
}

__global__ void finalize_kernel(const double* __restrict__ S,
                                const int* __restrict__ cnt,
                                float* __restrict__ out)
{
  if (threadIdx.x == 0){
    double lc = 0.0, lb = 0.0;
    for (int b = 0; b < NB; ++b){
      int c = cnt[b];
      double tot = (double)(c > 1 ? c : 1);
      lc += S[b]      / tot;
      lb += S[NB + b] / tot;
    }
    out[0] = (float)(lc / (double)NB);          // loss_cls
    out[1] = (float)(10.0 * lb / (double)NB);   // loss_bbox (BBOX_W = 10)
  }
}

extern "C" void kernel_launch(void* const* d_in, const int* in_sizes, int n_in,
                              void* d_out, int out_size, void* d_ws, size_t ws_size,
                              hipStream_t stream) {
  const float* cls  = (const float*)d_in[0];
  const float* bbox = (const float*)d_in[1];
  const float* gtb  = (const float*)d_in[2];
  const int*   gtl  = (const int*)d_in[3];
  const unsigned char* gmask = (const unsigned char*)d_in[4];

  double* S   = (double*)d_ws;          // 32 doubles
  int*    cnt = (int*)(S + 2 * NB);     // 16 ints

  // accumulators must be zeroed every call (harness does not re-poison)
  hipMemsetAsync(d_ws, 0, 2 * NB * sizeof(double) + NB * sizeof(int), stream);

  dim3 grid((N_ANCH + 255) / 256, NB);
  anchor_loss_kernel<<<grid, 256, 0, stream>>>(cls, bbox, gtb, gtl, gmask, S, cnt);
  finalize_kernel<<<1, 64, 0, stream>>>(S, cnt, (float*)d_out);
}

// Round 2
// 77.445 us; speedup vs baseline: 3.4636x; 3.4636x over previous
//
#include <hip/hip_runtime.h>
#include <hip/hip_bf16.h>

#define N_ANCH 49104
#define NB 16
#define NGT 100
#define NC 80

#define LOG2E 1.4426950408889634f
#define LN2   0.6931471805599453f

__device__ __forceinline__ float frcp(float x){ return __builtin_amdgcn_rcpf(x); }
__device__ __forceinline__ float fexp2(float x){ return __builtin_amdgcn_exp2f(x); }
__device__ __forceinline__ float flog2(float x){ return __builtin_amdgcn_logf(x); }

// t=0 focal term, unscaled by 0.75:  p(x)^2 * softplus(x)
__device__ __forceinline__ float f0_term(float x){
  float ax = fabsf(x);
  float u  = fexp2(-LOG2E * ax);        // e^{-|x|}
  float w  = 1.0f + u;
  float sp = fmaf(flog2(w), LN2, fmaxf(x, 0.f));   // softplus(x)
  float r  = frcp(w);                   // 1/(1+u)
  float p  = (x >= 0.f) ? r : 1.0f - r; // sigmoid(x)
  return p * p * sp;
}

// full parts for the label-class correction
__device__ __forceinline__ void sig_parts(float x, float& p, float& sp, float& spn){
  float ax = fabsf(x);
  float u  = fexp2(-LOG2E * ax);
  float w  = 1.0f + u;
  float l  = LN2 * flog2(w);            // softplus(-|x|)
  sp  = fmaxf(x, 0.f) + l;              // softplus(x)
  spn = fmaxf(-x, 0.f) + l;             // softplus(-x)
  float r = frcp(w);
  p = (x >= 0.f) ? r : 1.0f - r;
}

__global__ __launch_bounds__(256) void anchor_loss_kernel(
    const float* __restrict__ cls,
    const float* __restrict__ bbox,
    const float* __restrict__ gtb,
    const int*   __restrict__ gtl,
    const unsigned char* __restrict__ gmask,
    double* __restrict__ S,     // [32]: S_cls[16], S_bbox[16]
    int* __restrict__ cnt)      // [16]: pos count per image
{
  const int tid = threadIdx.x;
  const int b   = blockIdx.y;
  const int a   = blockIdx.x * 256 + tid;

  __shared__ float4 s_gt[NGT];
  __shared__ float  s_area[NGT];
  __shared__ int    s_label[NGT];
  __shared__ int    s_notfloat, s_offbyte;
  __shared__ float  s_rc[4], s_rb[4];
  __shared__ int    s_rp[4];

  if (tid == 0){ s_notfloat = 0; s_offbyte = 0; }
  __syncthreads();

  // ---- detect mask_labels storage layout (bool8 vs int32 vs float32) ----
  {
    const unsigned int* mw = (const unsigned int*)gmask;
    int nf = 0, ob = 0;
    for (int i = tid; i < (NB * NGT) / 4; i += 256){
      unsigned int w = mw[i];
      if (w != 0u && w != 0x3F800000u) nf = 1;   // not a {0,1.0f} float pattern
      if (w & 0xFFFFFF00u)             ob = 1;   // nonzero byte at off%4 != 0
    }
    if (nf) s_notfloat = 1;
    if (ob) s_offbyte  = 1;
  }
  __syncthreads();
  const bool byteLayout = (s_notfloat && s_offbyte);  // else: dword elements

  // ---- stage GT boxes; invalid GTs become degenerate (IoU == 0 exactly) ----
  for (int j = tid; j < NGT; j += 256){
    float4 g = ((const float4*)gtb)[b * NGT + j];
    int v;
    if (byteLayout) v = (gmask[b * NGT + j] != 0);
    else            v = (((const unsigned int*)gmask)[b * NGT + j] != 0u);
    if (!v){ g.x = 3e9f; g.y = 3e9f; g.z = 3e9f; g.w = 3e9f; }
    s_gt[j]    = g;
    s_area[j]  = (g.z - g.x) * (g.w - g.y);   // 0 for degenerate
    s_label[j] = gtl[b * NGT + j];
  }
  __syncthreads();

  float accC = 0.f, accB = 0.f;
  int posi = 0;

  if (a < N_ANCH){
    // ---- regenerate anchor a (RetinaNet grid) ----
    int f, lg, st, rel;
    if      (a < 36864){ f = 64; lg = 6; st = 8;   rel = a; }
    else if (a < 46080){ f = 32; lg = 5; st = 16;  rel = a - 36864; }
    else if (a < 48384){ f = 16; lg = 4; st = 32;  rel = a - 46080; }
    else if (a < 48960){ f = 8;  lg = 3; st = 64;  rel = a - 48384; }
    else               { f = 4;  lg = 2; st = 128; rel = a - 48960; }
    int cell = rel / 9;
    int k    = rel - cell * 9;
    int yy   = cell >> lg;
    int xx   = cell & (f - 1);
    int rr = (k >= 6) ? 2 : ((k >= 3) ? 1 : 0);   // ratio index
    int sc = k - rr * 3;                          // scale index
    double sq  = (rr == 0) ? 0.7071067811865476 : ((rr == 1) ? 1.0 : 1.4142135623730951);
    double scl = (sc == 0) ? 4.0 : ((sc == 1) ? 5.039684199579493 : 6.349604207872798);
    double ss  = (double)st * scl;
    double wd  = ss / sq, hd = ss * sq;
    double cxd = ((double)xx + 0.5) * (double)st;
    double cyd = ((double)yy + 0.5) * (double)st;
    float x1 = (float)(cxd - wd * 0.5);
    float y1 = (float)(cyd - hd * 0.5);
    float x2 = (float)(cxd + wd * 0.5);
    float y2 = (float)(cyd + hd * 0.5);
    float areaA = (x2 - x1) * (y2 - y1);

    // ---- division-free IoU argmax: track (Ib, Ub) with iou_b = Ib/Ub ----
    float Ib = -1.0f, Ub = 1.0f; int best = 0;
    #pragma unroll 4
    for (int j = 0; j < NGT; ++j){
      float4 g = s_gt[j];
      float lx = fmaxf(x1, g.x), ly = fmaxf(y1, g.y);
      float rx = fminf(x2, g.z), ry = fminf(y2, g.w);
      float iw = fmaxf(rx - lx, 0.f), ih = fmaxf(ry - ly, 0.f);
      float I  = iw * ih;
      float U  = fmaxf(areaA + s_area[j] - I, 1e-6f);
      bool gt = I * Ub > Ib * U;        // iou_j > iou_b (strict -> keeps first max)
      if (gt){ Ib = I; Ub = U; best = j; }
    }

    bool pos = 2.0f * Ib >= Ub;                        // iou >= 0.5
    bool ign = (!pos) && (5.0f * Ib >= 2.0f * Ub);     // 0.4 <= iou < 0.5

    if (pos){
      posi = 1;
      float4 g = s_gt[best];
      float aw = x2 - x1, ah = y2 - y1;
      float axc = (x1 + x2) * 0.5f, ayc = (y1 + y2) * 0.5f;
      float gw = fmaxf(g.z - g.x, 1e-6f), gh = fmaxf(g.w - g.y, 1e-6f);
      float gxc = (g.x + g.z) * 0.5f, gyc = (g.y + g.w) * 0.5f;
      float t0 = (gxc - axc) / aw, t1 = (gyc - ayc) / ah;
      float t2 = LN2 * flog2(gw * frcp(aw));
      float t3 = LN2 * flog2(gh * frcp(ah));
      float4 bp = ((const float4*)bbox)[(size_t)b * N_ANCH + a];
      const float BETA = 1.0f / 9.0f;
      float d0 = fabsf(bp.x - t0), d1 = fabsf(bp.y - t1);
      float d2 = fabsf(bp.z - t2), d3 = fabsf(bp.w - t3);
      accB += (d0 < BETA) ? 4.5f * d0 * d0 : d0 - 0.5f * BETA;
      accB += (d1 < BETA) ? 4.5f * d1 * d1 : d1 - 0.5f * BETA;
      accB += (d2 < BETA) ? 4.5f * d2 * d2 : d2 - 0.5f * BETA;
      accB += (d3 < BETA) ? 4.5f * d3 * d3 : d3 - 0.5f * BETA;
    }

    // ---- focal loss: branch-free t=0 sum over all classes ----
    float acc = 0.f;
    if (!ign){
      const float4* cp = (const float4*)(cls + (size_t)(b * N_ANCH + a) * NC);
      #pragma unroll 4
      for (int v = 0; v < NC / 4; ++v){
        float4 c4 = cp[v];
        acc += f0_term(c4.x);
        acc += f0_term(c4.y);
        acc += f0_term(c4.z);
        acc += f0_term(c4.w);
      }
    }
    accC = 0.75f * acc;
    if (pos){
      int label = s_label[best];
      float xl = cls[(size_t)(b * N_ANCH + a) * NC + label];   // L1 hit
      float p, sp, spn; sig_parts(xl, p, sp, spn);
      float omp = 1.0f - p;
      accC += 0.25f * omp * omp * spn - 0.75f * p * p * sp;    // f1 - f0
    }
  }

  // ---- block reduction: wave shuffle then cross-wave via LDS ----
  #pragma unroll
  for (int o = 32; o > 0; o >>= 1){
    accC += __shfl_down(accC, o);
    accB += __shfl_down(accB, o);
    posi += __shfl_down(posi, o);
  }
  int wave = tid >> 6, lane = tid & 63;
  if (lane == 0){ s_rc[wave] = accC; s_rb[wave] = accB; s_rp[wave] = posi; }
  __syncthreads();
  if (tid == 0){
    float c  = s_rc[0] + s_rc[1] + s_rc[2] + s_rc[3];
    float bb = s_rb[0] + s_rb[1] + s_rb[2] + s_rb[3];
    int   p  = s_rp[0] + s_rp[1] + s_rp[2] + s_rp[3];
    atomicAdd(&S[b],      (double)c);
    atomicAdd(&S[NB + b], (double)bb);
    atomicAdd(&cnt[b], p);
  }
}

__global__ void finalize_kernel(const double* __restrict__ S,
                                const int* __restrict__ cnt,
                                float* __restrict__ out)
{
  if (threadIdx.x == 0){
    double lc = 0.0, lb = 0.0;
    for (int b = 0; b < NB; ++b){
      int c = cnt[b];
      double tot = (double)(c > 1 ? c : 1);
      lc += S[b]      / tot;
      lb += S[NB + b] / tot;
    }
    out[0] = (float)(lc / (double)NB);          // loss_cls
    out[1] = (float)(10.0 * lb / (double)NB);   // loss_bbox (BBOX_W = 10)
  }
}

extern "C" void kernel_launch(void* const* d_in, const int* in_sizes, int n_in,
                              void* d_out, int out_size, void* d_ws, size_t ws_size,
                              hipStream_t stream) {
  const float* cls  = (const float*)d_in[0];
  const float* bbox = (const float*)d_in[1];
  const float* gtb  = (const float*)d_in[2];
  const int*   gtl  = (const int*)d_in[3];
  const unsigned char* gmask = (const unsigned char*)d_in[4];

  double* S   = (double*)d_ws;          // 32 doubles
  int*    cnt = (int*)(S + 2 * NB);     // 16 ints

  hipMemsetAsync(d_ws, 0, 2 * NB * sizeof(double) + NB * sizeof(int), stream);

  dim3 grid((N_ANCH + 255) / 256, NB);
  anchor_loss_kernel<<<grid, 256, 0, stream>>>(cls, bbox, gtb, gtl, gmask, S, cnt);
  finalize_kernel<<<1, 64, 0, stream>>>(S, cnt, (float*)d_out);
}